// Round 11
// baseline (189.397 us; speedup 1.0000x reference)
//
#include <hip/hip_runtime.h>

#define B_   32
#define Hh   28
#define Ww   28
#define Cc   192
#define T_   785
#define BT_  (B_ * T_)          // 25120
#define BTC_ ((size_t)BT_ * Cc) // 4823040
// 192^-0.5 * log2(e): softmax computed in exp2 domain
#define SCALE2 0.10412163388f

typedef __attribute__((ext_vector_type(8))) __bf16 bf16x8;
typedef __attribute__((ext_vector_type(4))) __bf16 bf16x4;
typedef __attribute__((ext_vector_type(4))) float  f32x4;

// ---------------------------------------------------------------------------
// Fused depthwise 3x3 conv + BN (3 branches), 1 output row per block for
// max parallelism (896 blocks; latency-bound kernel). grid (29, 32),
// block 192. bx==28 casts w_qkv/w_proj to bf16.
// ---------------------------------------------------------------------------
__global__ __launch_bounds__(192) void conv3_bn_k(
    const float* __restrict__ x, const float* __restrict__ cw,
    const float* __restrict__ g, const float* __restrict__ bb,
    const float* __restrict__ mu, const float* __restrict__ var,
    __bf16* __restrict__ y,
    const float* __restrict__ wqkv, const float* __restrict__ wproj,
    __bf16* __restrict__ wdst)
{
  const int c = threadIdx.x;
  const int h = blockIdx.x;
  const int b = blockIdx.y;
  if (h == Hh) {                       // weight cast blocks
    int t = b * 192 + c;               // 0..6143
    int base = t * 24;
    const float* src = (base < 3 * Cc * Cc) ? (wqkv + base)
                                            : (wproj + (base - 3 * Cc * Cc));
#pragma unroll
    for (int e = 0; e < 24; e += 4) {
      float4 v = *(const float4*)(src + e);
      wdst[base + e + 0] = (__bf16)v.x;
      wdst[base + e + 1] = (__bf16)v.y;
      wdst[base + e + 2] = (__bf16)v.z;
      wdst[base + e + 3] = (__bf16)v.w;
    }
    return;
  }
  float w9[3][9], sc[3], sh[3];
#pragma unroll
  for (int br = 0; br < 3; ++br) {
    sc[br] = g[br * Cc + c] * rsqrtf(var[br * Cc + c] + 1e-5f);
    sh[br] = bb[br * Cc + c] - mu[br * Cc + c] * sc[br];
#pragma unroll
    for (int k = 0; k < 9; ++k) w9[br][k] = cw[(br * Cc + c) * 9 + k];
  }
  const float* xb = x + (size_t)b * T_ * Cc;
  if (h == 0) {
#pragma unroll
    for (int br = 0; br < 3; ++br)
      y[br * BTC_ + (size_t)b * T_ * Cc + c] = (__bf16)xb[c];   // cls passthrough
  }
  float c0[3], c1[3], c2[3];
#pragma unroll
  for (int r = 0; r < 3; ++r) {
    int rr = h - 1 + r;
    c0[r] = 0.f;
    c1[r] = (rr >= 0 && rr < Hh) ? xb[(size_t)(1 + rr * Ww) * Cc + c] : 0.f;
  }
  for (int col = 0; col < Ww; ++col) {
#pragma unroll
    for (int r = 0; r < 3; ++r) {
      int rr = h - 1 + r, ci = col + 1;
      c2[r] = (rr >= 0 && rr < Hh && ci < Ww)
                ? xb[(size_t)(1 + rr * Ww + ci) * Cc + c] : 0.f;
    }
    size_t orow = (size_t)(b * T_ + 1 + h * Ww + col) * Cc + c;
#pragma unroll
    for (int br = 0; br < 3; ++br) {
      float acc = c0[0]*w9[br][0] + c1[0]*w9[br][1] + c2[0]*w9[br][2]
                + c0[1]*w9[br][3] + c1[1]*w9[br][4] + c2[1]*w9[br][5]
                + c0[2]*w9[br][6] + c1[2]*w9[br][7] + c2[2]*w9[br][8];
      y[br * BTC_ + orow] = (__bf16)(acc * sc[br] + sh[br]);
    }
#pragma unroll
    for (int r = 0; r < 3; ++r) { c0[r] = c1[r]; c1[r] = c2[r]; }
  }
}

// ---------------------------------------------------------------------------
// MFMA GEMM, full-N tile (128 x 192) — unchanged from round 8.
// ---------------------------------------------------------------------------
template <int MODE>
__global__ __launch_bounds__(512) void gemm_bf16(
    const __bf16* __restrict__ A0, const __bf16* __restrict__ W0,
    const float* __restrict__ bias, void* __restrict__ outp)
{
  __shared__ __bf16 As[128][72];
  __shared__ __bf16 Bs[192][72];
  const int z = blockIdx.z;
  const __bf16* A  = A0 + (MODE == 0 ? (size_t)z * BTC_ : 0);
  const __bf16* Bw = W0 + (MODE == 0 ? (size_t)z * Cc * Cc : 0);
  const float osc = (MODE == 0 && z == 0) ? SCALE2 : 1.0f;
  const int tid = threadIdx.x;
  const int wid = tid >> 6, l = tid & 63, c = l & 15, g = l >> 4;
  const int wm = wid >> 2, wn = wid & 3;
  const int m0 = blockIdx.x * 128;
  const int ar = tid >> 2, aq = tid & 3;
  const int brow = tid >> 3, bv = tid & 7;

  f32x4 acc[4][3];
#pragma unroll
  for (int i = 0; i < 4; ++i)
#pragma unroll
    for (int j = 0; j < 3; ++j) acc[i][j] = (f32x4)(0.f);

  const __bf16* ap = A + (size_t)(m0 + ar) * Cc + aq * 16;   // OOB rows land in mapped ws; stores guarded
  const __bf16* bp0 = Bw + (size_t)brow * Cc + bv * 8;
  uint4 a0 = *(const uint4*)(ap + 0);
  uint4 a1 = *(const uint4*)(ap + 8);
  uint4 b0 = *(const uint4*)(bp0);
  uint4 b1 = *(const uint4*)(bp0 + (size_t)64 * Cc);
  uint4 b2 = *(const uint4*)(bp0 + (size_t)128 * Cc);

  for (int kc = 0; kc < 3; ++kc) {
    __syncthreads();
    *(uint4*)&As[ar][aq * 16 + 0] = a0;
    *(uint4*)&As[ar][aq * 16 + 8] = a1;
    *(uint4*)&Bs[brow +   0][bv * 8] = b0;
    *(uint4*)&Bs[brow +  64][bv * 8] = b1;
    *(uint4*)&Bs[brow + 128][bv * 8] = b2;
    if (kc < 2) {
      ap += 64; bp0 += 64;
      a0 = *(const uint4*)(ap + 0);
      a1 = *(const uint4*)(ap + 8);
      b0 = *(const uint4*)(bp0);
      b1 = *(const uint4*)(bp0 + (size_t)64 * Cc);
      b2 = *(const uint4*)(bp0 + (size_t)128 * Cc);
    }
    __syncthreads();
#pragma unroll
    for (int ksl = 0; ksl < 2; ++ksl) {
      bf16x8 af[4], bfr[3];
#pragma unroll
      for (int mf = 0; mf < 4; ++mf)
        af[mf] = *(const bf16x8*)&As[wm * 64 + mf * 16 + c][ksl * 32 + g * 8];
#pragma unroll
      for (int nf = 0; nf < 3; ++nf)
        bfr[nf] = *(const bf16x8*)&Bs[wn * 48 + nf * 16 + c][ksl * 32 + g * 8];
#pragma unroll
      for (int mf = 0; mf < 4; ++mf)
#pragma unroll
        for (int nf = 0; nf < 3; ++nf)
          acc[mf][nf] = __builtin_amdgcn_mfma_f32_16x16x32_bf16(
              af[mf], bfr[nf], acc[mf][nf], 0, 0, 0);
    }
  }
  float bias_c[3] = {0.f, 0.f, 0.f};
  if (MODE == 1) {
#pragma unroll
    for (int nf = 0; nf < 3; ++nf) bias_c[nf] = bias[wn * 48 + nf * 16 + c];
  }
#pragma unroll
  for (int mf = 0; mf < 4; ++mf) {
#pragma unroll
    for (int i = 0; i < 4; ++i) {
      int m = m0 + wm * 64 + mf * 16 + g * 4 + i;
      if (m < BT_) {
#pragma unroll
        for (int nf = 0; nf < 3; ++nf) {
          int n = wn * 48 + nf * 16 + c;
          if (MODE == 1)
            ((float*)outp)[(size_t)m * Cc + n] = acc[mf][nf][i] + bias_c[nf];
          else
            ((__bf16*)outp)[z * BTC_ + (size_t)m * Cc + n] =
                (__bf16)(acc[mf][nf][i] * osc);
        }
      }
    }
  }
}

// ---------------------------------------------------------------------------
// MFMA flash attention v3: 8 waves / 128 q-rows per block SHARING one K/V
// staging (barriers amortized 2x, staging per thread halved, FETCH halved),
// XOR-swizzled LDS (write/read mappings verified bijective+consistent).
// Per-wave chain identical to r8 (the r4 lesson: keep the serial chain
// short, add parallel waves instead).
// grid 672 = 8 XCD chunks x 84 (12 (b,h) groups x 7 qt-pairs). 512 thr.
// ---------------------------------------------------------------------------
__global__ __launch_bounds__(512) void attn_mfma(
    const __bf16* __restrict__ qkv, __bf16* __restrict__ aout)
{
  __shared__ __bf16 Ks[64][72];      // [key][d]   (col 8-blocks XOR row&7)
  __shared__ __bf16 Vt[64][72];      // [d][key]   (col 8-blocks XOR row&7)
  __shared__ __bf16 Ps[8][16][72];   // per-wave [qrow][key] (8B blocks XOR c&6)
  const int bid = blockIdx.x;
  const int swz = (bid & 7) * 84 + (bid >> 3);
  const int qtp = swz % 7;                  // 128-row q-tile pair
  const int g2 = swz / 7;
  const int hh = g2 % 3;
  const int b  = g2 / 3;
  const int tid = threadIdx.x;
  const int wid = tid >> 6, l = tid & 63, c = l & 15, g = l >> 4;
  const __bf16* Q = qkv + ((size_t)(0 * B_ + b) * T_) * Cc + hh * 64;
  const __bf16* K = qkv + ((size_t)(1 * B_ + b) * T_) * Cc + hh * 64;
  const __bf16* V = qkv + ((size_t)(2 * B_ + b) * T_) * Cc + hh * 64;

  // Q fragments in registers (SCALE2 pre-folded). OOB q-rows (>=785) read
  // mapped ws garbage; their columns never get stored. Wave owns 16 rows.
  const int qrow = qtp * 128 + wid * 16 + c;
  const __bf16* qp = Q + (size_t)qrow * Cc + g * 8;
  bf16x8 qf0 = *(const bf16x8*)(qp);
  bf16x8 qf1 = *(const bf16x8*)(qp + 32);

  // staging roles: waves 0-3 stage K, waves 4-7 stage V (halved per-thread)
  const bool kRole = tid < 256;
  const int srow = tid >> 2, sq = tid & 3;          // K: row, col-quarter
  const int t2 = tid - 256;
  const int vkp = t2 & 31, vd0 = ((t2 >> 5) & 7) * 8; // V: key pair, d-octet
  const __bf16* kp  = K + (size_t)srow * Cc + sq * 16;
  const __bf16* vp0 = V + (size_t)(2 * vkp + 0) * Cc + vd0;
  const __bf16* vp1 = V + (size_t)(2 * vkp + 1) * Cc + vd0;

  f32x4 ot[4];
#pragma unroll
  for (int f = 0; f < 4; ++f) ot[f] = (f32x4)(0.f);
  float m_run = -1e30f, l_run = 0.f;

  for (int kt = 0; kt < 13; ++kt) {
    __syncthreads();                   // prev tile's LDS reads done
    if (kRole) {
      uint4 kr0 = *(const uint4*)(kp + 0);
      uint4 kr1 = *(const uint4*)(kp + 8);
      kp += 64 * Cc;
      // logical col 8-blocks {2sq, 2sq+1} -> phys ^ (row&7)
      *(uint4*)&Ks[srow][((2 * sq)     ^ (srow & 7)) * 8] = kr0;
      *(uint4*)&Ks[srow][((2 * sq + 1) ^ (srow & 7)) * 8] = kr1;
    } else {
      uint4 va = *(const uint4*)vp0;
      uint4 vb = *(const uint4*)vp1;
      vp0 += 64 * Cc; vp1 += 64 * Cc;
      const unsigned* aw = (const unsigned*)&va;
      const unsigned* bw = (const unsigned*)&vb;
#pragma unroll
      for (int w = 0; w < 4; ++w) {
        unsigned lo = __builtin_amdgcn_perm(bw[w], aw[w], 0x05040100u);
        unsigned hi = __builtin_amdgcn_perm(bw[w], aw[w], 0x07060302u);
        // rows r0=vd0+2w, r1=r0+1; key col 8-block vkp>>2, phys ^ (row&7)
        *(unsigned*)&Vt[vd0 + 2*w + 0][(((vkp >> 2) ^ ((2*w)     & 7)) * 8) + 2 * (vkp & 3)] = lo;
        *(unsigned*)&Vt[vd0 + 2*w + 1][(((vkp >> 2) ^ ((2*w + 1) & 7)) * 8) + 2 * (vkp & 3)] = hi;
      }
    }
    __syncthreads();

    // S^T = K . Q^T  (swizzled Ks reads: block b -> b ^ (c&7))
    f32x4 st[4];
#pragma unroll
    for (int f = 0; f < 4; ++f) st[f] = (f32x4)(0.f);
    __builtin_amdgcn_s_setprio(1);
#pragma unroll
    for (int f = 0; f < 4; ++f) {
      bf16x8 ka = *(const bf16x8*)&Ks[f * 16 + c][(g ^ (c & 7)) * 8];
      st[f] = __builtin_amdgcn_mfma_f32_16x16x32_bf16(ka, qf0, st[f], 0, 0, 0);
    }
#pragma unroll
    for (int f = 0; f < 4; ++f) {
      bf16x8 ka = *(const bf16x8*)&Ks[f * 16 + c][((4 + g) ^ (c & 7)) * 8];
      st[f] = __builtin_amdgcn_mfma_f32_16x16x32_bf16(ka, qf1, st[f], 0, 0, 0);
    }
    __builtin_amdgcn_s_setprio(0);

    if (kt == 12) {                    // mask keys >= 785 (local idx >= 17)
#pragma unroll
      for (int f = 0; f < 4; ++f)
#pragma unroll
        for (int i = 0; i < 4; ++i)
          if (f * 16 + g * 4 + i >= 17) st[f][i] = -1e30f;
    }
    // online softmax (exp2 domain, defer-max THR=8)
    float m01 = fmaxf(fmaxf(st[0][0], st[0][1]), fmaxf(st[0][2], st[0][3]));
    float m11 = fmaxf(fmaxf(st[1][0], st[1][1]), fmaxf(st[1][2], st[1][3]));
    float m21 = fmaxf(fmaxf(st[2][0], st[2][1]), fmaxf(st[2][2], st[2][3]));
    float m31 = fmaxf(fmaxf(st[3][0], st[3][1]), fmaxf(st[3][2], st[3][3]));
    float pmax = fmaxf(fmaxf(m01, m11), fmaxf(m21, m31));
    pmax = fmaxf(pmax, __shfl_xor(pmax, 16));
    pmax = fmaxf(pmax, __shfl_xor(pmax, 32));
    if (!__all(pmax <= m_run + 8.f)) {
      float mnew = fmaxf(m_run, pmax);
      float corr = exp2f(m_run - mnew);
      m_run = mnew;
      l_run *= corr;
#pragma unroll
      for (int f = 0; f < 4; ++f)
#pragma unroll
        for (int i = 0; i < 4; ++i) ot[f][i] *= corr;
    }
    float rs = 0.f;
#pragma unroll
    for (int f = 0; f < 4; ++f) {
      bf16x4 pk;
#pragma unroll
      for (int i = 0; i < 4; ++i) {
        float p = exp2f(st[f][i] - m_run);
        rs += p;
        pk[i] = (__bf16)p;
      }
      // logical 8B-block 4f+g -> phys ^ (c&6)  (bit0 preserved for b128 reads)
      *(bf16x4*)&Ps[wid][c][((4 * f + g) ^ (c & 6)) * 4] = pk;
    }
    rs += __shfl_xor(rs, 16);
    rs += __shfl_xor(rs, 32);
    l_run += rs;

    // O^T += V^T . P^T  (Ps read: 16B block B -> B ^ ((c>>1)&3); Vt: ^ c&7)
    __builtin_amdgcn_s_setprio(1);
#pragma unroll
    for (int s2 = 0; s2 < 2; ++s2) {
      bf16x8 pb2 = *(const bf16x8*)&Ps[wid][c][((s2 * 4 + g) ^ ((c >> 1) & 3)) * 8];
#pragma unroll
      for (int f = 0; f < 4; ++f) {
        bf16x8 va2 = *(const bf16x8*)&Vt[f * 16 + c][((s2 * 4 + g) ^ (c & 7)) * 8];
        ot[f] = __builtin_amdgcn_mfma_f32_16x16x32_bf16(va2, pb2, ot[f], 0, 0, 0);
      }
    }
    __builtin_amdgcn_s_setprio(0);
  }

  const int t = qtp * 128 + wid * 16 + c;
  if (t < T_) {
    float inv = 1.f / l_run;
    __bf16* op = aout + ((size_t)(b * T_ + t)) * Cc + hh * 64;
#pragma unroll
    for (int f = 0; f < 4; ++f) {
      bf16x4 ov;
#pragma unroll
      for (int i = 0; i < 4; ++i) ov[i] = (__bf16)(ot[f][i] * inv);
      *(bf16x4*)(op + f * 16 + g * 4) = ov;
    }
  }
}

// ---------------------------------------------------------------------------
extern "C" void kernel_launch(void* const* d_in, const int* in_sizes, int n_in,
                              void* d_out, int out_size, void* d_ws, size_t ws_size,
                              hipStream_t stream) {
  (void)in_sizes; (void)n_in; (void)out_size; (void)ws_size;
  const float* x        = (const float*)d_in[0];
  const float* conv_w   = (const float*)d_in[1];
  const float* bn_scale = (const float*)d_in[2];
  const float* bn_bias  = (const float*)d_in[3];
  const float* bn_mean  = (const float*)d_in[4];
  const float* bn_var   = (const float*)d_in[5];
  const float* w_qkv    = (const float*)d_in[6];
  const float* w_proj   = (const float*)d_in[7];
  const float* b_proj   = (const float*)d_in[8];

  __bf16* ybf  = (__bf16*)d_ws;            // 3 * BTC
  __bf16* qkvb = ybf + 3 * BTC_;           // 3 * BTC (attn OOB reads spill into aobf: mapped)
  __bf16* aobf = qkvb + 3 * BTC_;          // BTC
  __bf16* wq   = aobf + BTC_;              // 3*192*192
  __bf16* wp   = wq + 3 * Cc * Cc;         // 192*192

  conv3_bn_k<<<dim3(Hh + 1, B_), 192, 0, stream>>>(
      x, conv_w, bn_scale, bn_bias, bn_mean, bn_var, ybf, w_qkv, w_proj, wq);

  const int mblocks = (BT_ + 127) / 128;   // 197
  gemm_bf16<0><<<dim3(mblocks, 1, 3), 512, 0, stream>>>(ybf, wq, nullptr, qkvb);
  attn_mfma<<<672, 512, 0, stream>>>(qkvb, aobf);
  gemm_bf16<1><<<dim3(mblocks, 1, 1), 512, 0, stream>>>(aobf, wp, b_proj, d_out);
}